// Round 8
// baseline (975.511 us; speedup 1.0000x reference)
//
#include <hip/hip_runtime.h>
#include <hip/hip_bf16.h>
#include <math.h>

// FocusedLinearAttention — fused-split bf16 MFMA GEMMs + fp32 attention core.
// B=128, N=196, C=768, H=8, HD=96, FF=3, KS=5. M = B*N = 25088.
//
// Round-8: adaptive PRESPLIT GEMM path.
//   * If ws_size >= 240.6 MB: x pre-split once to x2 [M][1536] bf16 (hi|lo);
//     GEMM stages BOTH A and B via global_load_lds (source-swizzled, linear
//     dest) -> K-loop VALU is address-bumps only. x2/kv+ksum/y2 time-share one
//     77 MB region (x2 dead before kv written; kv dead before y2 written).
//   * Else: exact round-7 path (375 us qkv, verified absmax 0.0078).
// Round-7 verified facts: XOR-slot swizzle -> SQ_LDS_BANK_CONFLICT == 0;
// gload16 + pre-swizzled source is correct; FETCH 223 MB (B L2-resident).

#define MROWS 25088
#define CDIM 768
#define HDIM 96
#define NTOK 196
#define BHN 1024
#define K2 1536   // hi|lo concatenated K

typedef __attribute__((ext_vector_type(8))) short bf16x8;
typedef __attribute__((ext_vector_type(4))) float f32x4;

__device__ __forceinline__ short f2bf(float x) {  // RNE fp32->bf16
  unsigned u = __float_as_uint(x);
  unsigned r = (u + 0x7fffu + ((u >> 16) & 1u)) >> 16;
  return (short)r;
}
__device__ __forceinline__ float bf2f(short s) {
  return __uint_as_float(((unsigned)(unsigned short)s) << 16);
}

__device__ __forceinline__ void gload16(const short* g, short* l) {
  __builtin_amdgcn_global_load_lds(
      (const __attribute__((address_space(1))) void*)g,
      (__attribute__((address_space(3))) void*)l, 16, 0, 0);
}

// pack 2 fp32 -> 2 bf16 (RNE) returning bits; residuals out
__device__ __forceinline__ unsigned cvt2(float x, float y, float& rx, float& ry) {
  __hip_bfloat162 hb = __float22bfloat162_rn(make_float2(x, y));
  float2 hf = __bfloat1622float2(hb);
  rx = x - hf.x; ry = y - hf.y;
  unsigned u;
  __builtin_memcpy(&u, &hb, 4);
  return u;
}
__device__ __forceinline__ unsigned cvt2n(float x, float y) {  // no residual
  __hip_bfloat162 hb = __float22bfloat162_rn(make_float2(x, y));
  unsigned u;
  __builtin_memcpy(&u, &hb, 4);
  return u;
}

// ---------------------------------------------------------------------------
// split_wt: W fp32 [768 k][768 n] -> out bf16 [768 n][1536 k] (hi | lo), x4 W
// ---------------------------------------------------------------------------
__global__ __launch_bounds__(256) void split_wt(const float* __restrict__ W0,
                                                const float* __restrict__ W1,
                                                const float* __restrict__ W2,
                                                const float* __restrict__ W3,
                                                short* __restrict__ outbase) {
  const float* W;
  switch (blockIdx.z) {
    case 0: W = W0; break;
    case 1: W = W1; break;
    case 2: W = W2; break;
    default: W = W3; break;
  }
  short* O = outbase + (size_t)blockIdx.z * 768 * K2;
  __shared__ float t[32][33];
  const int n0 = blockIdx.x * 32, k0 = blockIdx.y * 32;
  const int tx = threadIdx.x & 31, ty = threadIdx.x >> 5;  // ty: 0..7
#pragma unroll
  for (int i = 0; i < 32; i += 8) t[ty + i][tx] = W[(size_t)(k0 + ty + i) * 768 + n0 + tx];
  __syncthreads();
#pragma unroll
  for (int i = 0; i < 32; i += 8) {
    float v = t[tx][ty + i];  // = W[k0+tx][n0+ty+i]
    short h = f2bf(v), l = f2bf(v - bf2f(h));
    O[(size_t)(n0 + ty + i) * K2 + k0 + tx] = h;
    O[(size_t)(n0 + ty + i) * K2 + 768 + k0 + tx] = l;
  }
}

// ---------------------------------------------------------------------------
// split_act: fp32 [nrows][768] -> bf16 [nrows][1536] (hi | lo). Memory-bound.
// ---------------------------------------------------------------------------
__global__ __launch_bounds__(256) void split_act(const float* __restrict__ in,
                                                 short* __restrict__ out2) {
  int idx = blockIdx.x * 256 + threadIdx.x;  // one per 4 elems
  if (idx >= MROWS * 192) return;
  int m = idx / 192, c4 = (idx % 192) * 4;
  float4 v = *(const float4*)&in[(size_t)m * CDIM + c4];
  short4 hi, lo;
  hi.x = f2bf(v.x); lo.x = f2bf(v.x - bf2f(hi.x));
  hi.y = f2bf(v.y); lo.y = f2bf(v.y - bf2f(hi.y));
  hi.z = f2bf(v.z); lo.z = f2bf(v.z - bf2f(hi.z));
  hi.w = f2bf(v.w); lo.w = f2bf(v.w - bf2f(hi.w));
  *(short4*)&out2[(size_t)m * K2 + c4] = hi;
  *(short4*)&out2[(size_t)m * K2 + 768 + c4] = lo;
}

// ---------------------------------------------------------------------------
// Shared GEMM geometry: 128x128 tile, BK=32, 4 waves 2x2, wave 64x64 via 4x4
// frags of 16x16x32 (48 MFMA/K-step incl. 3 split terms). LDS [128][32] shorts,
// 16B slots XOR-swizzled by (row>>1)&3 (verified conflict-free, round 7).
// ---------------------------------------------------------------------------

// ---- Round-7 body: A fp32, split inline via cvt_pk (fallback path) ----
__device__ __forceinline__ void gemm_mfma_body(const float* __restrict__ A,
                                               const short* __restrict__ Bt2,
                                               const float* __restrict__ bias,
                                               const float* __restrict__ pos,
                                               float* __restrict__ C, bool addPos) {
  __shared__ short Ah[128 * 32];
  __shared__ short Al[128 * 32];
  __shared__ short Bh[128 * 32];
  __shared__ short Bl[128 * 32];
  const int tid = threadIdx.x;
  const int lane = tid & 63;
  const int w = tid >> 6, wr = w >> 1, wc = w & 1;

  const int hw = blockIdx.x + 6 * blockIdx.y;
  const int tile = (hw & 7) * 147 + (hw >> 3);
  const int bx = tile % 6, by = tile / 6;
  const int row0 = by * 128, col0 = bx * 128;

  const int ar = tid >> 1;
  const int ah_ = tid & 1;
  const int am = (tid >> 2) & 3;
  const int s0 = (2 * ah_) ^ am, s1 = (2 * ah_ + 1) ^ am;
  const float* gA = A + (size_t)(row0 + ar) * CDIM + ah_ * 16;
  short* lAh0 = Ah + ar * 32 + s0 * 8;
  short* lAh1 = Ah + ar * 32 + s1 * 8;
  short* lAl0 = Al + ar * 32 + s0 * 8;
  short* lAl1 = Al + ar * 32 + s1 * 8;

  const int brow = w * 32 + (lane >> 2);
  const int bslot = (lane & 3) ^ ((lane >> 3) & 3);
  const short* gBh = Bt2 + (size_t)(col0 + brow) * K2 + bslot * 8;
  const short* gBl = gBh + 768;
  short* ldsBh0 = Bh + (w * 32) * 32;
  short* ldsBh1 = Bh + (w * 32 + 16) * 32;
  short* ldsBl0 = Bl + (w * 32) * 32;
  short* ldsBl1 = Bl + (w * 32 + 16) * 32;

  f32x4 acc[4][4];
#pragma unroll
  for (int i = 0; i < 4; i++)
#pragma unroll
    for (int j = 0; j < 4; j++) acc[i][j] = (f32x4){0.f, 0.f, 0.f, 0.f};

  const int fr = lane & 15;
  const int k16 = lane >> 4;
  const int rslot = k16 ^ ((fr >> 1) & 3);
  const int rofs = fr * 32 + rslot * 8;

#pragma unroll 1
  for (int k0 = 0; k0 < CDIM; k0 += 32) {
    float4 a0 = *(const float4*)(gA + k0);
    float4 a1 = *(const float4*)(gA + k0 + 4);
    float4 a2 = *(const float4*)(gA + k0 + 8);
    float4 a3 = *(const float4*)(gA + k0 + 12);
    float r[16];
    unsigned h0 = cvt2(a0.x, a0.y, r[0], r[1]);
    unsigned h1 = cvt2(a0.z, a0.w, r[2], r[3]);
    unsigned h2 = cvt2(a1.x, a1.y, r[4], r[5]);
    unsigned h3 = cvt2(a1.z, a1.w, r[6], r[7]);
    unsigned h4 = cvt2(a2.x, a2.y, r[8], r[9]);
    unsigned h5 = cvt2(a2.z, a2.w, r[10], r[11]);
    unsigned h6 = cvt2(a3.x, a3.y, r[12], r[13]);
    unsigned h7 = cvt2(a3.z, a3.w, r[14], r[15]);
    unsigned l0 = cvt2n(r[0], r[1]),  l1 = cvt2n(r[2], r[3]);
    unsigned l2 = cvt2n(r[4], r[5]),  l3 = cvt2n(r[6], r[7]);
    unsigned l4 = cvt2n(r[8], r[9]),  l5 = cvt2n(r[10], r[11]);
    unsigned l6 = cvt2n(r[12], r[13]), l7 = cvt2n(r[14], r[15]);

    __syncthreads();
    gload16(gBh + k0, ldsBh0);
    gload16(gBh + 16 * K2 + k0, ldsBh1);
    gload16(gBl + k0, ldsBl0);
    gload16(gBl + 16 * K2 + k0, ldsBl1);
    *(uint4*)lAh0 = make_uint4(h0, h1, h2, h3);
    *(uint4*)lAh1 = make_uint4(h4, h5, h6, h7);
    *(uint4*)lAl0 = make_uint4(l0, l1, l2, l3);
    *(uint4*)lAl1 = make_uint4(l4, l5, l6, l7);
    __syncthreads();

    bf16x8 fah[4], fal[4], fbh[4], fbl[4];
#pragma unroll
    for (int i = 0; i < 4; i++) {
      const int arr = (wr * 64 + i * 16) * 32 + rofs;
      const int brr = (wc * 64 + i * 16) * 32 + rofs;
      fah[i] = *(const bf16x8*)&Ah[arr];
      fal[i] = *(const bf16x8*)&Al[arr];
      fbh[i] = *(const bf16x8*)&Bh[brr];
      fbl[i] = *(const bf16x8*)&Bl[brr];
    }
#pragma unroll
    for (int i = 0; i < 4; i++)
#pragma unroll
      for (int j = 0; j < 4; j++)
        acc[i][j] = __builtin_amdgcn_mfma_f32_16x16x32_bf16(fah[i], fbh[j], acc[i][j], 0, 0, 0);
#pragma unroll
    for (int i = 0; i < 4; i++)
#pragma unroll
      for (int j = 0; j < 4; j++)
        acc[i][j] = __builtin_amdgcn_mfma_f32_16x16x32_bf16(fah[i], fbl[j], acc[i][j], 0, 0, 0);
#pragma unroll
    for (int i = 0; i < 4; i++)
#pragma unroll
      for (int j = 0; j < 4; j++)
        acc[i][j] = __builtin_amdgcn_mfma_f32_16x16x32_bf16(fal[i], fbh[j], acc[i][j], 0, 0, 0);
  }

  const int rg = (lane >> 4) * 4;
#pragma unroll
  for (int i = 0; i < 4; i++) {
#pragma unroll
    for (int j = 0; j < 4; j++) {
      f32x4 v = acc[i][j];
      const int gcol = col0 + wc * 64 + j * 16 + fr;
      const float bb = bias[gcol];
#pragma unroll
      for (int r2 = 0; r2 < 4; r2++) {
        const int grow = row0 + wr * 64 + i * 16 + rg + r2;
        float val = v[r2] + bb;
        if (addPos) val += pos[(grow % NTOK) * CDIM + gcol];
        C[(size_t)grow * CDIM + gcol] = val;
      }
    }
  }
}

// ---- PRESPLIT body: A and B both bf16 [row][1536], all staging via gload ----
__device__ __forceinline__ void gemm_mfma_body_pre(const short* __restrict__ A2,
                                                   const short* __restrict__ Bt2,
                                                   const float* __restrict__ bias,
                                                   const float* __restrict__ pos,
                                                   float* __restrict__ C, bool addPos) {
  __shared__ short Ah[128 * 32];
  __shared__ short Al[128 * 32];
  __shared__ short Bh[128 * 32];
  __shared__ short Bl[128 * 32];
  const int tid = threadIdx.x;
  const int lane = tid & 63;
  const int w = tid >> 6, wr = w >> 1, wc = w & 1;

  const int hw = blockIdx.x + 6 * blockIdx.y;
  const int tile = (hw & 7) * 147 + (hw >> 3);
  const int bx = tile % 6, by = tile / 6;
  const int row0 = by * 128, col0 = bx * 128;

  // staging map (identical for A and B): wave w stages rows [w*32, w*32+32);
  // per-lane source slot pre-swizzled, LDS dest linear (rule: gload_lds writes
  // base + lane*16). (row>>1)&3 == (lane>>3)&3 for row = w*32 + (lane>>2).
  const int srow = w * 32 + (lane >> 2);
  const int slot = (lane & 3) ^ ((lane >> 3) & 3);
  const short* gA = A2 + (size_t)(row0 + srow) * K2 + slot * 8;
  const short* gB = Bt2 + (size_t)(col0 + srow) * K2 + slot * 8;
  short* dA0 = Ah + (w * 32) * 32;
  short* dA1 = Ah + (w * 32 + 16) * 32;
  short* dAl0 = Al + (w * 32) * 32;
  short* dAl1 = Al + (w * 32 + 16) * 32;
  short* dB0 = Bh + (w * 32) * 32;
  short* dB1 = Bh + (w * 32 + 16) * 32;
  short* dBl0 = Bl + (w * 32) * 32;
  short* dBl1 = Bl + (w * 32 + 16) * 32;

  f32x4 acc[4][4];
#pragma unroll
  for (int i = 0; i < 4; i++)
#pragma unroll
    for (int j = 0; j < 4; j++) acc[i][j] = (f32x4){0.f, 0.f, 0.f, 0.f};

  const int fr = lane & 15;
  const int k16 = lane >> 4;
  const int rslot = k16 ^ ((fr >> 1) & 3);
  const int rofs = fr * 32 + rslot * 8;

#pragma unroll 1
  for (int k0 = 0; k0 < CDIM; k0 += 32) {
    __syncthreads();  // prev iteration's LDS reads complete
    gload16(gA + k0, dA0);
    gload16(gA + 16 * K2 + k0, dA1);
    gload16(gA + 768 + k0, dAl0);
    gload16(gA + 768 + 16 * K2 + k0, dAl1);
    gload16(gB + k0, dB0);
    gload16(gB + 16 * K2 + k0, dB1);
    gload16(gB + 768 + k0, dBl0);
    gload16(gB + 768 + 16 * K2 + k0, dBl1);
    __syncthreads();  // drains vmcnt (gload_lds) before reads

    bf16x8 fah[4], fal[4], fbh[4], fbl[4];
#pragma unroll
    for (int i = 0; i < 4; i++) {
      const int arr = (wr * 64 + i * 16) * 32 + rofs;
      const int brr = (wc * 64 + i * 16) * 32 + rofs;
      fah[i] = *(const bf16x8*)&Ah[arr];
      fal[i] = *(const bf16x8*)&Al[arr];
      fbh[i] = *(const bf16x8*)&Bh[brr];
      fbl[i] = *(const bf16x8*)&Bl[brr];
    }
#pragma unroll
    for (int i = 0; i < 4; i++)
#pragma unroll
      for (int j = 0; j < 4; j++)
        acc[i][j] = __builtin_amdgcn_mfma_f32_16x16x32_bf16(fah[i], fbh[j], acc[i][j], 0, 0, 0);
#pragma unroll
    for (int i = 0; i < 4; i++)
#pragma unroll
      for (int j = 0; j < 4; j++)
        acc[i][j] = __builtin_amdgcn_mfma_f32_16x16x32_bf16(fah[i], fbl[j], acc[i][j], 0, 0, 0);
#pragma unroll
    for (int i = 0; i < 4; i++)
#pragma unroll
      for (int j = 0; j < 4; j++)
        acc[i][j] = __builtin_amdgcn_mfma_f32_16x16x32_bf16(fal[i], fbh[j], acc[i][j], 0, 0, 0);
  }

  const int rg = (lane >> 4) * 4;
#pragma unroll
  for (int i = 0; i < 4; i++) {
#pragma unroll
    for (int j = 0; j < 4; j++) {
      f32x4 v = acc[i][j];
      const int gcol = col0 + wc * 64 + j * 16 + fr;
      const float bb = bias[gcol];
#pragma unroll
      for (int r2 = 0; r2 < 4; r2++) {
        const int grow = row0 + wr * 64 + i * 16 + rg + r2;
        float val = v[r2] + bb;
        if (addPos) val += pos[(grow % NTOK) * CDIM + gcol];
        C[(size_t)grow * CDIM + gcol] = val;
      }
    }
  }
}

__global__ __launch_bounds__(256) void mfma_qkv(const float* __restrict__ x,
    const short* __restrict__ wt2,
    const float* __restrict__ b0, const float* __restrict__ b1, const float* __restrict__ b2,
    const float* __restrict__ pos,
    float* __restrict__ o0, float* __restrict__ o1, float* __restrict__ o2) {
  const short* Bt; const float* bias; float* C; bool addPos = false;
  switch (blockIdx.z) {
    case 0: Bt = wt2;                         bias = b0; C = o0; break;
    case 1: Bt = wt2 + (size_t)768 * K2;      bias = b1; C = o1; addPos = true; break;
    default: Bt = wt2 + (size_t)2 * 768 * K2; bias = b2; C = o2; break;
  }
  gemm_mfma_body(x, Bt, bias, pos, C, addPos);
}

__global__ __launch_bounds__(256) void mfma_proj(const float* __restrict__ y,
    const short* __restrict__ wt2p, const float* __restrict__ bias,
    float* __restrict__ C) {
  gemm_mfma_body(y, wt2p, bias, nullptr, C, false);
}

__global__ __launch_bounds__(256) void mfma_qkv_pre(const short* __restrict__ x2,
    const short* __restrict__ wt2,
    const float* __restrict__ b0, const float* __restrict__ b1, const float* __restrict__ b2,
    const float* __restrict__ pos,
    float* __restrict__ o0, float* __restrict__ o1, float* __restrict__ o2) {
  const short* Bt; const float* bias; float* C; bool addPos = false;
  switch (blockIdx.z) {
    case 0: Bt = wt2;                         bias = b0; C = o0; break;
    case 1: Bt = wt2 + (size_t)768 * K2;      bias = b1; C = o1; addPos = true; break;
    default: Bt = wt2 + (size_t)2 * 768 * K2; bias = b2; C = o2; break;
  }
  gemm_mfma_body_pre(x2, Bt, bias, pos, C, addPos);
}

__global__ __launch_bounds__(256) void mfma_proj_pre(const short* __restrict__ y2,
    const short* __restrict__ wt2p, const float* __restrict__ bias,
    float* __restrict__ C) {
  gemm_mfma_body_pre(y2, wt2p, bias, nullptr, C, false);
}

// ---------------------------------------------------------------------------
// Focusing, wave-per-row: t=(relu+1e-6)/softplus(sp); u=t^3; out=u*||t||/||u||
// ---------------------------------------------------------------------------
__device__ __forceinline__ void wave_reduce2(float& a, float& b) {
#pragma unroll
  for (int off = 32; off > 0; off >>= 1) {
    a += __shfl_xor(a, off, 64);
    b += __shfl_xor(b, off, 64);
  }
}

__global__ __launch_bounds__(256) void focus_kernel(float* __restrict__ q,
                                                    float* __restrict__ k,
                                                    const float* __restrict__ sp) {
  const int row = blockIdx.x * 4 + (threadIdx.x >> 6);
  const int lane = threadIdx.x & 63;
  float* qb = q + (size_t)row * CDIM;
  float* kb = k + (size_t)row * CDIM;

  float tq[12], tk[12];
  float sq = 0.f, sk = 0.f;
#pragma unroll
  for (int s = 0; s < 3; s++) {
    const int c = s * 256 + lane * 4;
    float4 qv = *(const float4*)&qb[c];
    float4 kv4 = *(const float4*)&kb[c];
    float4 spv = *(const float4*)&sp[c];
#pragma unroll
    for (int j = 0; j < 4; j++) {
      float scp = j == 0 ? spv.x : j == 1 ? spv.y : j == 2 ? spv.z : spv.w;
      float qq  = j == 0 ? qv.x  : j == 1 ? qv.y  : j == 2 ? qv.z  : qv.w;
      float kk  = j == 0 ? kv4.x : j == 1 ? kv4.y : j == 2 ? kv4.z : kv4.w;
      float scale = fmaxf(scp, 0.f) + log1pf(expf(-fabsf(scp)));  // softplus
      float inv = 1.f / scale;
      float aq = (fmaxf(qq, 0.f) + 1e-6f) * inv;
      float ak = (fmaxf(kk, 0.f) + 1e-6f) * inv;
      tq[s * 4 + j] = aq; tk[s * 4 + j] = ak;
      sq += aq * aq; sk += ak * ak;
    }
  }
  wave_reduce2(sq, sk);
  const float nq1 = sqrtf(sq), nk1 = sqrtf(sk);

  float s2q = 0.f, s2k = 0.f;
#pragma unroll
  for (int j = 0; j < 12; j++) {
    float cq = tq[j] * tq[j] * tq[j];
    float ck = tk[j] * tk[j] * tk[j];
    s2q += cq * cq; s2k += ck * ck;
  }
  wave_reduce2(s2q, s2k);
  const float rq = nq1 / sqrtf(s2q);
  const float rk = nk1 / sqrtf(s2k);

#pragma unroll
  for (int s = 0; s < 3; s++) {
    const int c = s * 256 + lane * 4;
    float4 oq, ok;
#pragma unroll
    for (int j = 0; j < 4; j++) {
      float a = tq[s * 4 + j], b = tk[s * 4 + j];
      float vq = a * a * a * rq, vk = b * b * b * rk;
      if (j == 0) { oq.x = vq; ok.x = vk; }
      else if (j == 1) { oq.y = vq; ok.y = vk; }
      else if (j == 2) { oq.z = vq; ok.z = vk; }
      else { oq.w = vq; ok.w = vk; }
    }
    *(float4*)&qb[c] = oq;
    *(float4*)&kb[c] = ok;
  }
}

// ---------------------------------------------------------------------------
// ksum[bh][d] = sum_j k_head[j][d]
// ---------------------------------------------------------------------------
__global__ __launch_bounds__(128) void ksum_kernel(const float* __restrict__ k,
                                                   float* __restrict__ ksum) {
  const int bh = blockIdx.x;
  const int b = bh >> 3, h = bh & 7;
  const int d = threadIdx.x;
  if (d >= HDIM) return;
  const float* base = k + (size_t)(b * NTOK) * CDIM + h * HDIM + d;
  float s = 0.f;
  for (int j = 0; j < NTOK; ++j) s += base[(size_t)j * CDIM];
  ksum[bh * HDIM + d] = s;
}

// ---------------------------------------------------------------------------
// kv[bh] = k_head^T @ v_head : (96x196)@(196x96). 256 thr (16x16), 6x6/thr.
// ---------------------------------------------------------------------------
__global__ __launch_bounds__(256) void kv_kernel(const float* __restrict__ k,
                                                 const float* __restrict__ v,
                                                 float* __restrict__ kv) {
  const int bh = blockIdx.x;
  const int b = bh >> 3, h = bh & 7;
  const size_t base = (size_t)(b * NTOK) * CDIM + h * HDIM;
  __shared__ float ks[28][96];
  __shared__ float vs[28][96];
  const int tid = threadIdx.x;
  const int tx = tid & 15, ty = tid >> 4;
  float acc[6][6];
#pragma unroll
  for (int i = 0; i < 6; i++)
#pragma unroll
    for (int j = 0; j < 6; j++) acc[i][j] = 0.f;

  for (int j0 = 0; j0 < NTOK; j0 += 28) {
    for (int idx = tid; idx < 28 * 96; idx += 256) {
      int jr = idx / 96, d = idx % 96;
      size_t g = base + (size_t)(j0 + jr) * CDIM + d;
      ks[jr][d] = k[g];
      vs[jr][d] = v[g];
    }
    __syncthreads();
#pragma unroll 4
    for (int j = 0; j < 28; ++j) {
      float a[6], bb[6];
#pragma unroll
      for (int i = 0; i < 6; i++) a[i] = ks[j][ty * 6 + i];
#pragma unroll
      for (int i = 0; i < 6; i++) bb[i] = vs[j][tx * 6 + i];
#pragma unroll
      for (int i = 0; i < 6; i++)
#pragma unroll
        for (int jj = 0; jj < 6; jj++) acc[i][jj] += a[i] * bb[jj];
    }
    __syncthreads();
  }
#pragma unroll
  for (int i = 0; i < 6; i++)
#pragma unroll
    for (int j = 0; j < 6; j++)
      kv[(size_t)bh * (HDIM * HDIM) + (ty * 6 + i) * HDIM + tx * 6 + j] = acc[i][j];
}

// ---------------------------------------------------------------------------
// y[i][d] = z_i * sum_c q[i][c]*kv[c][d], z_i = 1/(q_i . ksum + 1e-6)
// ---------------------------------------------------------------------------
__global__ __launch_bounds__(256) void attn_out_kernel(const float* __restrict__ q,
                                                       const float* __restrict__ kvmat,
                                                       const float* __restrict__ ksum,
                                                       float* __restrict__ y) {
  const int bh = blockIdx.x;
  const int b = bh >> 3, h = bh & 7;
  const size_t base = (size_t)(b * NTOK) * CDIM + h * HDIM;
  __shared__ float kvs[HDIM * HDIM];
  __shared__ float qs[64][97];
  __shared__ float ksum_s[HDIM];
  const int tid = threadIdx.x;
  const int tx = tid & 15, ty = tid >> 4;
  const int d0 = tx * 6;

  for (int idx = tid; idx < HDIM * HDIM; idx += 256) kvs[idx] = kvmat[(size_t)bh * (HDIM * HDIM) + idx];
  if (tid < HDIM) ksum_s[tid] = ksum[bh * HDIM + tid];

  for (int i0 = 0; i0 < NTOK; i0 += 64) {
    int nrows = NTOK - i0; if (nrows > 64) nrows = 64;
    __syncthreads();
    for (int idx = tid; idx < nrows * 96; idx += 256) {
      int rr = idx / 96, d = idx % 96;
      qs[rr][d] = q[base + (size_t)(i0 + rr) * CDIM + d];
    }
    __syncthreads();

    float zz[4];
#pragma unroll
    for (int rr = 0; rr < 4; rr++) {
      int r2 = ty * 4 + rr;
      float part = 0.f;
#pragma unroll
      for (int i = 0; i < 6; i++) part += qs[r2][d0 + i] * ksum_s[d0 + i];
#pragma unroll
      for (int m = 8; m >= 1; m >>= 1) part += __shfl_xor(part, m, 16);
      zz[rr] = 1.f / (part + 1e-6f);
    }

    float acc[4][6];
#pragma unroll
    for (int rr = 0; rr < 4; rr++)
#pragma unroll
      for (int i = 0; i < 6; i++) acc[rr][i] = 0.f;

    for (int c = 0; c < HDIM; ++c) {
      float kvv[6];
#pragma unroll
      for (int i = 0; i < 6; i++) kvv[i] = kvs[c * HDIM + d0 + i];
#pragma unroll
      for (int rr = 0; rr < 4; rr++) {
        float qv = qs[ty * 4 + rr][c];
#pragma unroll
        for (int i = 0; i < 6; i++) acc[rr][i] += qv * kvv[i];
      }
    }
#pragma unroll
    for (int rr = 0; rr < 4; rr++) {
      int r2 = i0 + ty * 4 + rr;
      if (r2 < NTOK) {
#pragma unroll
        for (int i = 0; i < 6; i++) y[base + (size_t)r2 * CDIM + d0 + i] = acc[rr][i] * zz[rr];
      }
    }
  }
}

// ---------------------------------------------------------------------------
// Depthwise 5x5 conv on v (14x14 image per (bh,ch)); y += conv + dwc_b
// ---------------------------------------------------------------------------
__global__ __launch_bounds__(256) void dwconv_kernel(const float* __restrict__ v,
                                                     const float* __restrict__ w,
                                                     const float* __restrict__ bias,
                                                     float* __restrict__ y) {
  const int bh = blockIdx.x;
  const int b = bh >> 3, h = bh & 7;
  const int ch0 = blockIdx.y * 32;
  const size_t base = (size_t)(b * NTOK) * CDIM + h * HDIM + ch0;
  __shared__ float vs[NTOK][32];
  __shared__ float ws_s[32][25];
  const int tid = threadIdx.x;

  for (int idx = tid; idx < NTOK * 32; idx += 256) {
    int j = idx >> 5, ch = idx & 31;
    vs[j][ch] = v[base + (size_t)j * CDIM + ch];
  }
  for (int idx = tid; idx < 32 * 25; idx += 256) {
    int ch = idx / 25, kk = idx % 25;
    ws_s[ch][kk] = w[(ch0 + ch) * 25 + kk];
  }
  __syncthreads();

  const int ch = tid & 31, pg = tid >> 5;
  const float bval = bias[ch0 + ch];
  for (int p = pg; p < NTOK; p += 8) {
    int r2 = p / 14, cl = p % 14;
    float acc = 0.f;
#pragma unroll
    for (int dr = 0; dr < 5; dr++) {
      int rr = r2 + dr - 2;
      if (rr < 0 || rr >= 14) continue;
#pragma unroll
      for (int dc = 0; dc < 5; dc++) {
        int cc = cl + dc - 2;
        if (cc < 0 || cc >= 14) continue;
        acc += vs[rr * 14 + cc][ch] * ws_s[ch][dr * 5 + dc];
      }
    }
    y[base + (size_t)p * CDIM + ch] += acc + bval;
  }
}

// ---------------------------------------------------------------------------
extern "C" void kernel_launch(void* const* d_in, const int* in_sizes, int n_in,
                              void* d_out, int out_size, void* d_ws, size_t ws_size,
                              hipStream_t stream) {
  const float* x    = (const float*)d_in[0];
  const float* Wq   = (const float*)d_in[1];
  const float* bq   = (const float*)d_in[2];
  const float* Wk   = (const float*)d_in[3];
  const float* bk   = (const float*)d_in[4];
  const float* Wv   = (const float*)d_in[5];
  const float* bv   = (const float*)d_in[6];
  const float* pos  = (const float*)d_in[7];
  const float* sp   = (const float*)d_in[8];
  const float* dwcw = (const float*)d_in[9];
  const float* dwcb = (const float*)d_in[10];
  const float* Wp   = (const float*)d_in[11];
  const float* bp   = (const float*)d_in[12];
  float* out = (float*)d_out;

  const size_t MC = (size_t)MROWS * CDIM;        // 19,267,584 elems
  const size_t WT2B = (size_t)4 * 768 * K2 * 2;  // 9,437,184 B
  const size_t X2B = (size_t)MROWS * K2 * 2;     // 77,070,336 B
  char* ws = (char*)d_ws;
  float* k    = (float*)(ws);                    // 77.07 MB (becomes y)
  float* v    = (float*)(ws + MC * 4);           // 77.07 MB
  short* wt2  = (short*)(ws + 2 * MC * 4);       // 9.44 MB
  // R3 region (77.07 MB): holds x2, THEN kv+ksum, THEN y2 (strictly sequential
  // lifetimes: x2 dead after mfma_qkv; kv/ksum dead after attn_out).
  char* R3 = ws + 2 * MC * 4 + WT2B;
  short* x2   = (short*)R3;
  float* kv   = (float*)R3;
  float* ksum = (float*)(R3 + (size_t)BHN * HDIM * HDIM * 4);
  short* y2   = (short*)R3;
  float* q = out;   // q lives in d_out; dead before mfma_proj overwrites it
  float* y = k;

  const size_t NEED = 2 * MC * 4 + WT2B + X2B;   // 240,648,192 B
  const bool pre = (ws_size >= NEED);            // constant per session -> graph-safe

  // 0) weight split+transpose
  split_wt<<<dim3(24, 24, 4), 256, 0, stream>>>(Wq, Wk, Wv, Wp, wt2);
  // 1) QKV projections (+bias, +pos on k)
  if (pre) {
    split_act<<<(MROWS * 192 + 255) / 256, 256, 0, stream>>>(x, x2);
    mfma_qkv_pre<<<dim3(6, 196, 3), 256, 0, stream>>>(x2, wt2, bq, bk, bv, pos, q, k, v);
  } else {
    mfma_qkv<<<dim3(6, 196, 3), 256, 0, stream>>>(x, wt2, bq, bk, bv, pos, q, k, v);
  }
  // 2) focusing (in-place on q, k)
  focus_kernel<<<MROWS / 4, 256, 0, stream>>>(q, k, sp);
  // 3) per-head k column sums (kv region now free: x2 dead)
  ksum_kernel<<<BHN, 128, 0, stream>>>(k, ksum);
  // 4) kv = k^T v per head
  kv_kernel<<<BHN, 256, 0, stream>>>(k, v, kv);
  // 5) y = (q @ kv) * z  (overwrites k buffer; q consumed)
  attn_out_kernel<<<BHN, 256, 0, stream>>>(q, kv, ksum, y);
  // 6) y += depthwise conv(v) + bias
  dwconv_kernel<<<dim3(BHN, 3), 256, 0, stream>>>(v, dwcw, dwcb, y);
  // 7) final projection (kv/ksum dead -> y2 reuses R3)
  if (pre) {
    split_act<<<(MROWS * 192 + 255) / 256, 256, 0, stream>>>(y, y2);
    mfma_proj_pre<<<dim3(6, 196, 1), 256, 0, stream>>>(y2, wt2 + (size_t)3 * 768 * K2, bp, out);
  } else {
    mfma_proj<<<dim3(6, 196, 1), 256, 0, stream>>>(y, wt2 + (size_t)3 * 768 * K2, bp, out);
  }
}

// Round 9
// 931.753 us; speedup vs baseline: 1.0470x; 1.0470x over previous
//
#include <hip/hip_runtime.h>
#include <hip/hip_bf16.h>
#include <math.h>

// FocusedLinearAttention — fused-split bf16 MFMA GEMMs + fp32 attention core.
// B=128, N=196, C=768, H=8, HD=96, FF=3, KS=5. M = B*N = 25088.
//
// Round-9: tail fusions (GEMM bodies identical to round-8 measured state).
//   * ksum fused into kv_kernel (summed from staged LDS tiles) — one less
//     77-MB pass + dispatch.
//   * dwconv writes y2 (bf16 hi|lo) directly -> second split_act deleted.
//   * kv/attn_out inner LDS reads vectorized to float2.
// Round-8 verified: ws_size >= 240.6 MB (presplit ran); swizzle conflict-free;
// qkv_pre = 330 us at MfmaUtil 36% (2-barrier structure ceiling).

#define MROWS 25088
#define CDIM 768
#define HDIM 96
#define NTOK 196
#define BHN 1024
#define K2 1536   // hi|lo concatenated K

typedef __attribute__((ext_vector_type(8))) short bf16x8;
typedef __attribute__((ext_vector_type(4))) float f32x4;

__device__ __forceinline__ short f2bf(float x) {  // RNE fp32->bf16
  unsigned u = __float_as_uint(x);
  unsigned r = (u + 0x7fffu + ((u >> 16) & 1u)) >> 16;
  return (short)r;
}
__device__ __forceinline__ float bf2f(short s) {
  return __uint_as_float(((unsigned)(unsigned short)s) << 16);
}

__device__ __forceinline__ void gload16(const short* g, short* l) {
  __builtin_amdgcn_global_load_lds(
      (const __attribute__((address_space(1))) void*)g,
      (__attribute__((address_space(3))) void*)l, 16, 0, 0);
}

// ---------------------------------------------------------------------------
// split_wt: W fp32 [768 k][768 n] -> out bf16 [768 n][1536 k] (hi | lo), x4 W
// ---------------------------------------------------------------------------
__global__ __launch_bounds__(256) void split_wt(const float* __restrict__ W0,
                                                const float* __restrict__ W1,
                                                const float* __restrict__ W2,
                                                const float* __restrict__ W3,
                                                short* __restrict__ outbase) {
  const float* W;
  switch (blockIdx.z) {
    case 0: W = W0; break;
    case 1: W = W1; break;
    case 2: W = W2; break;
    default: W = W3; break;
  }
  short* O = outbase + (size_t)blockIdx.z * 768 * K2;
  __shared__ float t[32][33];
  const int n0 = blockIdx.x * 32, k0 = blockIdx.y * 32;
  const int tx = threadIdx.x & 31, ty = threadIdx.x >> 5;  // ty: 0..7
#pragma unroll
  for (int i = 0; i < 32; i += 8) t[ty + i][tx] = W[(size_t)(k0 + ty + i) * 768 + n0 + tx];
  __syncthreads();
#pragma unroll
  for (int i = 0; i < 32; i += 8) {
    float v = t[tx][ty + i];  // = W[k0+tx][n0+ty+i]
    short h = f2bf(v), l = f2bf(v - bf2f(h));
    O[(size_t)(n0 + ty + i) * K2 + k0 + tx] = h;
    O[(size_t)(n0 + ty + i) * K2 + 768 + k0 + tx] = l;
  }
}

// ---------------------------------------------------------------------------
// split_act: fp32 [nrows][768] -> bf16 [nrows][1536] (hi | lo). Memory-bound.
// ---------------------------------------------------------------------------
__global__ __launch_bounds__(256) void split_act(const float* __restrict__ in,
                                                 short* __restrict__ out2) {
  int idx = blockIdx.x * 256 + threadIdx.x;  // one per 4 elems
  if (idx >= MROWS * 192) return;
  int m = idx / 192, c4 = (idx % 192) * 4;
  float4 v = *(const float4*)&in[(size_t)m * CDIM + c4];
  short4 hi, lo;
  hi.x = f2bf(v.x); lo.x = f2bf(v.x - bf2f(hi.x));
  hi.y = f2bf(v.y); lo.y = f2bf(v.y - bf2f(hi.y));
  hi.z = f2bf(v.z); lo.z = f2bf(v.z - bf2f(hi.z));
  hi.w = f2bf(v.w); lo.w = f2bf(v.w - bf2f(hi.w));
  *(short4*)&out2[(size_t)m * K2 + c4] = hi;
  *(short4*)&out2[(size_t)m * K2 + 768 + c4] = lo;
}

// ---------------------------------------------------------------------------
// PRESPLIT GEMM body: A and B bf16 [row][1536] (hi|lo), staged via gload_lds
// (source-swizzled, linear dest). 128x128 tile, BK=32, 4 waves 2x2, wave 64x64
// via 4x4 frags of 16x16x32; 3 split terms = 48 MFMA/K-step. LDS [128][32]
// shorts, 16B slots XOR-swizzled by (row>>1)&3 (verified conflict-free).
// ---------------------------------------------------------------------------
__device__ __forceinline__ void gemm_mfma_body_pre(const short* __restrict__ A2,
                                                   const short* __restrict__ Bt2,
                                                   const float* __restrict__ bias,
                                                   const float* __restrict__ pos,
                                                   float* __restrict__ C, bool addPos) {
  __shared__ short Ah[128 * 32];
  __shared__ short Al[128 * 32];
  __shared__ short Bh[128 * 32];
  __shared__ short Bl[128 * 32];
  const int tid = threadIdx.x;
  const int lane = tid & 63;
  const int w = tid >> 6, wr = w >> 1, wc = w & 1;

  const int hw = blockIdx.x + 6 * blockIdx.y;
  const int tile = (hw & 7) * 147 + (hw >> 3);
  const int bx = tile % 6, by = tile / 6;
  const int row0 = by * 128, col0 = bx * 128;

  const int srow = w * 32 + (lane >> 2);
  const int slot = (lane & 3) ^ ((lane >> 3) & 3);
  const short* gA = A2 + (size_t)(row0 + srow) * K2 + slot * 8;
  const short* gB = Bt2 + (size_t)(col0 + srow) * K2 + slot * 8;
  short* dA0 = Ah + (w * 32) * 32;
  short* dA1 = Ah + (w * 32 + 16) * 32;
  short* dAl0 = Al + (w * 32) * 32;
  short* dAl1 = Al + (w * 32 + 16) * 32;
  short* dB0 = Bh + (w * 32) * 32;
  short* dB1 = Bh + (w * 32 + 16) * 32;
  short* dBl0 = Bl + (w * 32) * 32;
  short* dBl1 = Bl + (w * 32 + 16) * 32;

  f32x4 acc[4][4];
#pragma unroll
  for (int i = 0; i < 4; i++)
#pragma unroll
    for (int j = 0; j < 4; j++) acc[i][j] = (f32x4){0.f, 0.f, 0.f, 0.f};

  const int fr = lane & 15;
  const int k16 = lane >> 4;
  const int rslot = k16 ^ ((fr >> 1) & 3);
  const int rofs = fr * 32 + rslot * 8;

#pragma unroll 1
  for (int k0 = 0; k0 < CDIM; k0 += 32) {
    __syncthreads();
    gload16(gA + k0, dA0);
    gload16(gA + 16 * K2 + k0, dA1);
    gload16(gA + 768 + k0, dAl0);
    gload16(gA + 768 + 16 * K2 + k0, dAl1);
    gload16(gB + k0, dB0);
    gload16(gB + 16 * K2 + k0, dB1);
    gload16(gB + 768 + k0, dBl0);
    gload16(gB + 768 + 16 * K2 + k0, dBl1);
    __syncthreads();

    bf16x8 fah[4], fal[4], fbh[4], fbl[4];
#pragma unroll
    for (int i = 0; i < 4; i++) {
      const int arr = (wr * 64 + i * 16) * 32 + rofs;
      const int brr = (wc * 64 + i * 16) * 32 + rofs;
      fah[i] = *(const bf16x8*)&Ah[arr];
      fal[i] = *(const bf16x8*)&Al[arr];
      fbh[i] = *(const bf16x8*)&Bh[brr];
      fbl[i] = *(const bf16x8*)&Bl[brr];
    }
#pragma unroll
    for (int i = 0; i < 4; i++)
#pragma unroll
      for (int j = 0; j < 4; j++)
        acc[i][j] = __builtin_amdgcn_mfma_f32_16x16x32_bf16(fah[i], fbh[j], acc[i][j], 0, 0, 0);
#pragma unroll
    for (int i = 0; i < 4; i++)
#pragma unroll
      for (int j = 0; j < 4; j++)
        acc[i][j] = __builtin_amdgcn_mfma_f32_16x16x32_bf16(fah[i], fbl[j], acc[i][j], 0, 0, 0);
#pragma unroll
    for (int i = 0; i < 4; i++)
#pragma unroll
      for (int j = 0; j < 4; j++)
        acc[i][j] = __builtin_amdgcn_mfma_f32_16x16x32_bf16(fal[i], fbh[j], acc[i][j], 0, 0, 0);
  }

  const int rg = (lane >> 4) * 4;
#pragma unroll
  for (int i = 0; i < 4; i++) {
#pragma unroll
    for (int j = 0; j < 4; j++) {
      f32x4 v = acc[i][j];
      const int gcol = col0 + wc * 64 + j * 16 + fr;
      const float bb = bias[gcol];
#pragma unroll
      for (int r2 = 0; r2 < 4; r2++) {
        const int grow = row0 + wr * 64 + i * 16 + rg + r2;
        float val = v[r2] + bb;
        if (addPos) val += pos[(grow % NTOK) * CDIM + gcol];
        C[(size_t)grow * CDIM + gcol] = val;
      }
    }
  }
}

__global__ __launch_bounds__(256) void mfma_qkv_pre(const short* __restrict__ x2,
    const short* __restrict__ wt2,
    const float* __restrict__ b0, const float* __restrict__ b1, const float* __restrict__ b2,
    const float* __restrict__ pos,
    float* __restrict__ o0, float* __restrict__ o1, float* __restrict__ o2) {
  const short* Bt; const float* bias; float* C; bool addPos = false;
  switch (blockIdx.z) {
    case 0: Bt = wt2;                         bias = b0; C = o0; break;
    case 1: Bt = wt2 + (size_t)768 * K2;      bias = b1; C = o1; addPos = true; break;
    default: Bt = wt2 + (size_t)2 * 768 * K2; bias = b2; C = o2; break;
  }
  gemm_mfma_body_pre(x2, Bt, bias, pos, C, addPos);
}

__global__ __launch_bounds__(256) void mfma_proj_pre(const short* __restrict__ y2,
    const short* __restrict__ wt2p, const float* __restrict__ bias,
    float* __restrict__ C) {
  gemm_mfma_body_pre(y2, wt2p, bias, nullptr, C, false);
}

// ---------------------------------------------------------------------------
// Focusing, wave-per-row: t=(relu+1e-6)/softplus(sp); u=t^3; out=u*||t||/||u||
// ---------------------------------------------------------------------------
__device__ __forceinline__ void wave_reduce2(float& a, float& b) {
#pragma unroll
  for (int off = 32; off > 0; off >>= 1) {
    a += __shfl_xor(a, off, 64);
    b += __shfl_xor(b, off, 64);
  }
}

__global__ __launch_bounds__(256) void focus_kernel(float* __restrict__ q,
                                                    float* __restrict__ k,
                                                    const float* __restrict__ sp) {
  const int row = blockIdx.x * 4 + (threadIdx.x >> 6);
  const int lane = threadIdx.x & 63;
  float* qb = q + (size_t)row * CDIM;
  float* kb = k + (size_t)row * CDIM;

  float tq[12], tk[12];
  float sq = 0.f, sk = 0.f;
#pragma unroll
  for (int s = 0; s < 3; s++) {
    const int c = s * 256 + lane * 4;
    float4 qv = *(const float4*)&qb[c];
    float4 kv4 = *(const float4*)&kb[c];
    float4 spv = *(const float4*)&sp[c];
#pragma unroll
    for (int j = 0; j < 4; j++) {
      float scp = j == 0 ? spv.x : j == 1 ? spv.y : j == 2 ? spv.z : spv.w;
      float qq  = j == 0 ? qv.x  : j == 1 ? qv.y  : j == 2 ? qv.z  : qv.w;
      float kk  = j == 0 ? kv4.x : j == 1 ? kv4.y : j == 2 ? kv4.z : kv4.w;
      float scale = fmaxf(scp, 0.f) + log1pf(expf(-fabsf(scp)));  // softplus
      float inv = 1.f / scale;
      float aq = (fmaxf(qq, 0.f) + 1e-6f) * inv;
      float ak = (fmaxf(kk, 0.f) + 1e-6f) * inv;
      tq[s * 4 + j] = aq; tk[s * 4 + j] = ak;
      sq += aq * aq; sk += ak * ak;
    }
  }
  wave_reduce2(sq, sk);
  const float nq1 = sqrtf(sq), nk1 = sqrtf(sk);

  float s2q = 0.f, s2k = 0.f;
#pragma unroll
  for (int j = 0; j < 12; j++) {
    float cq = tq[j] * tq[j] * tq[j];
    float ck = tk[j] * tk[j] * tk[j];
    s2q += cq * cq; s2k += ck * ck;
  }
  wave_reduce2(s2q, s2k);
  const float rq = nq1 / sqrtf(s2q);
  const float rk = nk1 / sqrtf(s2k);

#pragma unroll
  for (int s = 0; s < 3; s++) {
    const int c = s * 256 + lane * 4;
    float4 oq, ok;
#pragma unroll
    for (int j = 0; j < 4; j++) {
      float a = tq[s * 4 + j], b = tk[s * 4 + j];
      float vq = a * a * a * rq, vk = b * b * b * rk;
      if (j == 0) { oq.x = vq; ok.x = vk; }
      else if (j == 1) { oq.y = vq; ok.y = vk; }
      else if (j == 2) { oq.z = vq; ok.z = vk; }
      else { oq.w = vq; ok.w = vk; }
    }
    *(float4*)&qb[c] = oq;
    *(float4*)&kb[c] = ok;
  }
}

// ---------------------------------------------------------------------------
// kv[bh] = k_head^T @ v_head (96x196)@(196x96)  +  ksum[bh][d] = sum_j k[j][d]
// 256 thr (16x16), 6x6/thr; ksum summed from the staged LDS k-tiles.
// ---------------------------------------------------------------------------
__global__ __launch_bounds__(256) void kv_kernel(const float* __restrict__ k,
                                                 const float* __restrict__ v,
                                                 float* __restrict__ kv,
                                                 float* __restrict__ ksum) {
  const int bh = blockIdx.x;
  const int b = bh >> 3, h = bh & 7;
  const size_t base = (size_t)(b * NTOK) * CDIM + h * HDIM;
  __shared__ float ks[28][96];
  __shared__ float vs[28][96];
  const int tid = threadIdx.x;
  const int tx = tid & 15, ty = tid >> 4;
  float acc[6][6];
#pragma unroll
  for (int i = 0; i < 6; i++)
#pragma unroll
    for (int j = 0; j < 6; j++) acc[i][j] = 0.f;
  float kcol = 0.f;  // ksum accumulator (tid < 96)

  for (int j0 = 0; j0 < NTOK; j0 += 28) {
    for (int idx = tid; idx < 28 * 96; idx += 256) {
      int jr = idx / 96, d = idx % 96;
      size_t g = base + (size_t)(j0 + jr) * CDIM + d;
      ks[jr][d] = k[g];
      vs[jr][d] = v[g];
    }
    __syncthreads();
    if (tid < 96) {
#pragma unroll
      for (int jr = 0; jr < 28; ++jr) kcol += ks[jr][tid];
    }
#pragma unroll 4
    for (int j = 0; j < 28; ++j) {
      float a[6], bb[6];
#pragma unroll
      for (int i = 0; i < 3; i++) *(float2*)&a[i * 2]  = *(const float2*)&ks[j][ty * 6 + i * 2];
#pragma unroll
      for (int i = 0; i < 3; i++) *(float2*)&bb[i * 2] = *(const float2*)&vs[j][tx * 6 + i * 2];
#pragma unroll
      for (int i = 0; i < 6; i++)
#pragma unroll
        for (int jj = 0; jj < 6; jj++) acc[i][jj] += a[i] * bb[jj];
    }
    __syncthreads();
  }
#pragma unroll
  for (int i = 0; i < 6; i++)
#pragma unroll
    for (int j = 0; j < 6; j++)
      kv[(size_t)bh * (HDIM * HDIM) + (ty * 6 + i) * HDIM + tx * 6 + j] = acc[i][j];
  if (tid < 96) ksum[bh * HDIM + tid] = kcol;
}

// ---------------------------------------------------------------------------
// y[i][d] = z_i * sum_c q[i][c]*kv[c][d], z_i = 1/(q_i . ksum + 1e-6)
// ---------------------------------------------------------------------------
__global__ __launch_bounds__(256) void attn_out_kernel(const float* __restrict__ q,
                                                       const float* __restrict__ kvmat,
                                                       const float* __restrict__ ksum,
                                                       float* __restrict__ y) {
  const int bh = blockIdx.x;
  const int b = bh >> 3, h = bh & 7;
  const size_t base = (size_t)(b * NTOK) * CDIM + h * HDIM;
  __shared__ float kvs[HDIM * HDIM];
  __shared__ float qs[64][97];
  __shared__ float ksum_s[HDIM];
  const int tid = threadIdx.x;
  const int tx = tid & 15, ty = tid >> 4;
  const int d0 = tx * 6;

  for (int idx = tid; idx < HDIM * HDIM; idx += 256) kvs[idx] = kvmat[(size_t)bh * (HDIM * HDIM) + idx];
  if (tid < HDIM) ksum_s[tid] = ksum[bh * HDIM + tid];

  for (int i0 = 0; i0 < NTOK; i0 += 64) {
    int nrows = NTOK - i0; if (nrows > 64) nrows = 64;
    __syncthreads();
    for (int idx = tid; idx < nrows * 96; idx += 256) {
      int rr = idx / 96, d = idx % 96;
      qs[rr][d] = q[base + (size_t)(i0 + rr) * CDIM + d];
    }
    __syncthreads();

    float zz[4];
#pragma unroll
    for (int rr = 0; rr < 4; rr++) {
      int r2 = ty * 4 + rr;
      float part = 0.f;
#pragma unroll
      for (int i = 0; i < 6; i++) part += qs[r2][d0 + i] * ksum_s[d0 + i];
#pragma unroll
      for (int m = 8; m >= 1; m >>= 1) part += __shfl_xor(part, m, 16);
      zz[rr] = 1.f / (part + 1e-6f);
    }

    float acc[4][6];
#pragma unroll
    for (int rr = 0; rr < 4; rr++)
#pragma unroll
      for (int i = 0; i < 6; i++) acc[rr][i] = 0.f;

    for (int c = 0; c < HDIM; ++c) {
      float kvv[6];
#pragma unroll
      for (int i = 0; i < 3; i++) *(float2*)&kvv[i * 2] = *(const float2*)&kvs[c * HDIM + d0 + i * 2];
#pragma unroll
      for (int rr = 0; rr < 4; rr++) {
        float qv = qs[ty * 4 + rr][c];
#pragma unroll
        for (int i = 0; i < 6; i++) acc[rr][i] += qv * kvv[i];
      }
    }
#pragma unroll
    for (int rr = 0; rr < 4; rr++) {
      int r2 = i0 + ty * 4 + rr;
      if (r2 < NTOK) {
#pragma unroll
        for (int i = 0; i < 6; i++) y[base + (size_t)r2 * CDIM + d0 + i] = acc[rr][i] * zz[rr];
      }
    }
  }
}

// ---------------------------------------------------------------------------
// Depthwise 5x5 conv on v; y2 = split(y + conv + dwc_b)  [bf16 hi|lo out]
// ---------------------------------------------------------------------------
__global__ __launch_bounds__(256) void dwconv_kernel(const float* __restrict__ v,
                                                     const float* __restrict__ w,
                                                     const float* __restrict__ bias,
                                                     const float* __restrict__ y,
                                                     short* __restrict__ y2) {
  const int bh = blockIdx.x;
  const int b = bh >> 3, h = bh & 7;
  const int ch0 = blockIdx.y * 32;
  const size_t base = (size_t)(b * NTOK) * CDIM + h * HDIM + ch0;
  const size_t col = h * HDIM + ch0;  // column offset within 768
  __shared__ float vs[NTOK][32];
  __shared__ float ws_s[32][25];
  const int tid = threadIdx.x;

  for (int idx = tid; idx < NTOK * 32; idx += 256) {
    int j = idx >> 5, ch = idx & 31;
    vs[j][ch] = v[base + (size_t)j * CDIM + ch];
  }
  for (int idx = tid; idx < 32 * 25; idx += 256) {
    int ch = idx / 25, kk = idx % 25;
    ws_s[ch][kk] = w[(ch0 + ch) * 25 + kk];
  }
  __syncthreads();

  const int ch = tid & 31, pg = tid >> 5;
  const float bval = bias[ch0 + ch];
  for (int p = pg; p < NTOK; p += 8) {
    int r2 = p / 14, cl = p % 14;
    float acc = 0.f;
#pragma unroll
    for (int dr = 0; dr < 5; dr++) {
      int rr = r2 + dr - 2;
      if (rr < 0 || rr >= 14) continue;
#pragma unroll
      for (int dc = 0; dc < 5; dc++) {
        int cc = cl + dc - 2;
        if (cc < 0 || cc >= 14) continue;
        acc += vs[rr * 14 + cc][ch] * ws_s[ch][dr * 5 + dc];
      }
    }
    float val = y[base + (size_t)p * CDIM + ch] + acc + bval;
    short hh = f2bf(val);
    short ll = f2bf(val - bf2f(hh));
    const size_t row = (size_t)(b * NTOK + p);
    y2[row * K2 + col + ch] = hh;
    y2[row * K2 + 768 + col + ch] = ll;
  }
}

// ---------------------------------------------------------------------------
extern "C" void kernel_launch(void* const* d_in, const int* in_sizes, int n_in,
                              void* d_out, int out_size, void* d_ws, size_t ws_size,
                              hipStream_t stream) {
  const float* x    = (const float*)d_in[0];
  const float* Wq   = (const float*)d_in[1];
  const float* bq   = (const float*)d_in[2];
  const float* Wk   = (const float*)d_in[3];
  const float* bk   = (const float*)d_in[4];
  const float* Wv   = (const float*)d_in[5];
  const float* bv   = (const float*)d_in[6];
  const float* pos  = (const float*)d_in[7];
  const float* sp   = (const float*)d_in[8];
  const float* dwcw = (const float*)d_in[9];
  const float* dwcb = (const float*)d_in[10];
  const float* Wp   = (const float*)d_in[11];
  const float* bp   = (const float*)d_in[12];
  float* out = (float*)d_out;

  const size_t MC = (size_t)MROWS * CDIM;        // 19,267,584 elems
  const size_t WT2B = (size_t)4 * 768 * K2 * 2;  // 9,437,184 B
  char* ws = (char*)d_ws;
  float* k    = (float*)(ws);                    // 77.07 MB (becomes y)
  float* v    = (float*)(ws + MC * 4);           // 77.07 MB
  short* wt2  = (short*)(ws + 2 * MC * 4);       // 9.44 MB
  // R3 (77.07 MB), sequential lifetimes: x2 -> (kv,ksum) -> y2.
  // (ws_size >= 240.6 MB verified on this harness, round 8.)
  char* R3 = ws + 2 * MC * 4 + WT2B;
  short* x2   = (short*)R3;
  float* kv   = (float*)R3;
  float* ksum = (float*)(R3 + (size_t)BHN * HDIM * HDIM * 4);
  short* y2   = (short*)R3;
  float* q = out;   // q lives in d_out; dead before mfma_proj overwrites it
  float* y = k;

  // 0) weight split+transpose
  split_wt<<<dim3(24, 24, 4), 256, 0, stream>>>(Wq, Wk, Wv, Wp, wt2);
  // 1) x -> x2 (bf16 hi|lo); QKV projections (+bias, +pos on k)
  split_act<<<(MROWS * 192 + 255) / 256, 256, 0, stream>>>(x, x2);
  mfma_qkv_pre<<<dim3(6, 196, 3), 256, 0, stream>>>(x2, wt2, bq, bk, bv, pos, q, k, v);
  // 2) focusing (in-place on q, k)
  focus_kernel<<<MROWS / 4, 256, 0, stream>>>(q, k, sp);
  // 3) kv = k^T v per head + fused ksum (x2 dead -> R3 reused)
  kv_kernel<<<BHN, 256, 0, stream>>>(k, v, kv, ksum);
  // 4) y = (q @ kv) * z  (overwrites k buffer; q consumed)
  attn_out_kernel<<<BHN, 256, 0, stream>>>(q, kv, ksum, y);
  // 5) y2 = split(y + dwconv(v) + bias)  (kv/ksum dead -> R3 reused)
  dwconv_kernel<<<dim3(BHN, 3), 256, 0, stream>>>(v, dwcw, dwcb, y, y2);
  // 6) final projection
  mfma_proj_pre<<<dim3(6, 196, 1), 256, 0, stream>>>(y2, wt2 + (size_t)3 * 768 * K2, bp, out);
}